// Round 7
// baseline (149.593 us; speedup 1.0000x reference)
//
#include <hip/hip_runtime.h>
#include <hip/hip_bf16.h>
#include <math.h>

#define NROWS 131072
#define NCODE 512
#define DIM 128
#define ROWS_B 128

typedef __attribute__((ext_vector_type(8))) short short8v;
typedef __attribute__((ext_vector_type(16))) float f32x16;

__device__ inline short f2bf(float v) {
    __hip_bfloat16 h = __float2bfloat16(v);
    return *reinterpret_cast<short*>(&h);
}

// ||e||^2 per code (fp32 exact)
__global__ void e2_kernel(const float* __restrict__ emb, float* __restrict__ e2) {
    int c = blockIdx.x * blockDim.x + threadIdx.x;
    if (c < NCODE) {
        const float* e = emb + (size_t)c * DIM;
        float s = 0.f;
        #pragma unroll
        for (int l = 0; l < DIM; ++l) s = fmaf(e[l], e[l], s);
        e2[c] = s;
    }
}

// Pack emb into MFMA A-fragment lane order (bf16):
//   ahp[((mt*8)+kk)*64 + lane] = bf16(emb[code = mt*32 + (lane&31)][kk*16 + (lane>>5)*8 .. +8])
// -> vq_main A-loads are fully coalesced (64 lanes x 16B contiguous).
__global__ __launch_bounds__(256) void prep_pack(const float* __restrict__ emb,
        short8v* __restrict__ ahp) {
    int gid = blockIdx.x * 256 + threadIdx.x;       // 32 blocks x 256 = 8192
    int lane = gid & 63, kk = (gid >> 6) & 7, c32 = gid >> 9;
    int code = c32 * 32 + (lane & 31);
    int d0 = kk * 16 + (lane >> 5) * 8;
    const float* src = emb + (size_t)code * DIM + d0;
    float4 v0 = *reinterpret_cast<const float4*>(src);
    float4 v1 = *reinterpret_cast<const float4*>(src + 4);
    float f[8] = {v0.x, v0.y, v0.z, v0.w, v1.x, v1.y, v1.z, v1.w};
    short8v h;
    #pragma unroll
    for (int j = 0; j < 8; ++j) h[j] = f2bf(f[j]);
    ahp[gid] = h;
}

// D[m=code][n=row]; code = CB + (r&3) + 8*(r>>2) + 4*g, row = NT*32 + (lane&31).
#define PROC(ACC, CB, NT)                                                  \
    _Pragma("unroll")                                                      \
    for (int r = 0; r < 16; ++r) {                                         \
        int code = (CB) + (r & 3) + 8 * (r >> 2) + 4 * g;                  \
        float sv = e2s[code] - 2.0f * (ACC)[r];                            \
        if (sv < m1_##NT) { m1_##NT = sv; i1_##NT = code; }                \
    }

#define XMERGE(NT) {                                                       \
    float pm1 = __shfl_xor(m1_##NT, 32);                                   \
    int   pi  = __shfl_xor(i1_##NT, 32);                                   \
    bool pb = (pm1 < m1_##NT) || (pm1 == m1_##NT && pi < i1_##NT);         \
    if (pb) { m1_##NT = pm1; i1_##NT = pi; }                               \
}

__global__ __launch_bounds__(256, 3) void vq_main(
        const float* __restrict__ x, const float* __restrict__ emb,
        const short8v* __restrict__ ahp, const float* __restrict__ e2g,
        unsigned int* __restrict__ hist,
        float* __restrict__ out0, float* __restrict__ out1, float* __restrict__ out2) {
    __shared__ short xs[ROWS_B][DIM];   // XOR-swizzled: short index d ^ ((row&15)<<3)
    __shared__ float e2s[NCODE];
    __shared__ float x2s[ROWS_B];
    __shared__ float wm1[4][ROWS_B];
    __shared__ int   wi1[4][ROWS_B];
    __shared__ int   s_idx[ROWS_B];
    __shared__ float s_fin[ROWS_B];

    const int tid = threadIdx.x;
    const long row0 = (long)blockIdx.x * ROWS_B;

    // ---- stage x -> bf16 in LDS (swizzled), coalesced float4 ----
    const float4* xg = reinterpret_cast<const float4*>(x + row0 * DIM);
    #pragma unroll
    for (int it = 0; it < 16; ++it) {
        int i = tid + it * 256;
        int r = i >> 5, d0 = (i & 31) * 4;
        float4 v = xg[i];
        short4 h;
        h.x = f2bf(v.x); h.y = f2bf(v.y); h.z = f2bf(v.z); h.w = f2bf(v.w);
        int dd = d0 ^ ((r & 15) << 3);
        *reinterpret_cast<short4*>(&xs[r][dd]) = h;
    }
    for (int i = tid; i < NCODE; i += 256) e2s[i] = e2g[i];
    // ---- x2 per row (fp32 exact; L1/L2-hot re-read): 2 threads per row ----
    {
        int r = tid >> 1, q = tid & 1;
        const float4* xr = reinterpret_cast<const float4*>(x + (row0 + r) * DIM + q * 64);
        float s = 0.f;
        #pragma unroll
        for (int jj = 0; jj < 16; ++jj) {
            float4 v = xr[jj];
            s = fmaf(v.x, v.x, s); s = fmaf(v.y, v.y, s);
            s = fmaf(v.z, v.z, s); s = fmaf(v.w, v.w, s);
        }
        s += __shfl_down(s, 1, 64);
        if (q == 0) x2s[r] = s;
    }
    __syncthreads();

    const int wv = tid >> 6, lane = tid & 63;
    const int l31 = lane & 31, g = lane >> 5;
    const int bsw = (l31 & 15) << 3;

    float m1_0 = 1e30f; int i1_0 = 0;
    float m1_1 = 1e30f; int i1_1 = 0;
    float m1_2 = 1e30f; int i1_2 = 0;
    float m1_3 = 1e30f; int i1_3 = 0;

    // ---- wave wv owns codes [wv*128, wv*128+128): 4 M-tiles x all 128 rows ----
    // per kk-step: 1 coalesced A-load feeds 4 MFMAs (B from LDS, cheap)
    #pragma unroll 1
    for (int cc = 0; cc < 4; ++cc) {
        const int mt = wv * 4 + cc;
        f32x16 a0 = {}, a1 = {}, a2 = {}, a3 = {};

        #pragma unroll
        for (int kk = 0; kk < 8; ++kk) {
            short8v ah = ahp[(mt * 8 + kk) * 64 + lane];

            const int dd = (kk * 16 + g * 8) ^ bsw;
            short8v bh0 = *reinterpret_cast<const short8v*>(&xs[l31][dd]);
            short8v bh1 = *reinterpret_cast<const short8v*>(&xs[32 + l31][dd]);
            short8v bh2 = *reinterpret_cast<const short8v*>(&xs[64 + l31][dd]);
            short8v bh3 = *reinterpret_cast<const short8v*>(&xs[96 + l31][dd]);

            a0 = __builtin_amdgcn_mfma_f32_32x32x16_bf16(ah, bh0, a0, 0, 0, 0);
            a1 = __builtin_amdgcn_mfma_f32_32x32x16_bf16(ah, bh1, a1, 0, 0, 0);
            a2 = __builtin_amdgcn_mfma_f32_32x32x16_bf16(ah, bh2, a2, 0, 0, 0);
            a3 = __builtin_amdgcn_mfma_f32_32x32x16_bf16(ah, bh3, a3, 0, 0, 0);
        }
        const int cb = mt * 32;
        PROC(a0, cb, 0)
        PROC(a1, cb, 1)
        PROC(a2, cb, 2)
        PROC(a3, cb, 3)
    }

    // merge complementary code-halves (lane r <-> r+32, same row)
    XMERGE(0)
    XMERGE(1)
    XMERGE(2)
    XMERGE(3)
    if (lane < 32) {
        wm1[wv][l31]      = m1_0; wi1[wv][l31]      = i1_0;
        wm1[wv][32 + l31] = m1_1; wi1[wv][32 + l31] = i1_1;
        wm1[wv][64 + l31] = m1_2; wi1[wv][64 + l31] = i1_2;
        wm1[wv][96 + l31] = m1_3; wi1[wv][96 + l31] = i1_3;
    }
    __syncthreads();

    // ---- cross-wave merge (4 code-groups) ----
    if (tid < ROWS_B) {
        float m1 = wm1[0][tid]; int i1 = wi1[0][tid];
        #pragma unroll
        for (int w = 1; w < 4; ++w) {
            float pm1 = wm1[w][tid]; int pi = wi1[w][tid];
            bool pb = (pm1 < m1) || (pm1 == m1 && pi < i1);
            if (pb) { m1 = pm1; i1 = pi; }
        }
        s_idx[tid] = i1; s_fin[tid] = m1;
    }
    __syncthreads();

    // ---- out0: gather selected codebook rows (exact fp32) ----
    float4* o0 = reinterpret_cast<float4*>(out0 + row0 * DIM);
    #pragma unroll
    for (int it = 0; it < 16; ++it) {
        int i = tid + it * 256;
        int r = i >> 5, j = i & 31;
        int code = s_idx[r];
        o0[i] = reinterpret_cast<const float4*>(emb + (size_t)code * DIM)[j];
    }
    // ---- out1/out2 + histogram ----
    if (tid < ROWS_B) {
        float o = x2s[tid] + s_fin[tid];   // ||x||^2 + (||e||^2 - 2 x.e); err ~1e-4 << 4.24
        out1[row0 + tid] = o;
        out2[row0 + tid] = o;
        atomicAdd(&hist[s_idx[tid]], 1u);
    }
}

__global__ void entropy_kernel(const unsigned int* __restrict__ hist, float* __restrict__ oent) {
    __shared__ float red[8];
    int tid = threadIdx.x;  // 512 threads
    float p = (float)hist[tid] * (1.0f / 131072.0f);
    float t = (p > 0.f) ? (-p * logf(p)) : 0.f;
    #pragma unroll
    for (int off = 32; off > 0; off >>= 1) t += __shfl_down(t, off);
    if ((tid & 63) == 0) red[tid >> 6] = t;
    __syncthreads();
    if (tid == 0) {
        float s = 0.f;
        #pragma unroll
        for (int i = 0; i < 8; ++i) s += red[i];
        *oent = s;
    }
}

extern "C" void kernel_launch(void* const* d_in, const int* in_sizes, int n_in,
                              void* d_out, int out_size, void* d_ws, size_t ws_size,
                              hipStream_t stream) {
    const float* x   = (const float*)d_in[0];
    const float* emb = (const float*)d_in[1];
    float* out  = (float*)d_out;
    float* out0 = out;
    float* out1 = out0 + (size_t)NROWS * DIM;
    float* out2 = out1 + NROWS;
    float* oent = out2 + NROWS;

    unsigned int* hist = (unsigned int*)d_ws;
    float* e2g = (float*)((char*)d_ws + 4096);
    short8v* ahp = (short8v*)((char*)d_ws + 8192);

    hipMemsetAsync(d_ws, 0, 4096, stream);   // zero histogram (ws is poisoned, not re-zeroed)
    e2_kernel<<<2, 256, 0, stream>>>(emb, e2g);
    prep_pack<<<32, 256, 0, stream>>>(emb, ahp);
    vq_main<<<NROWS / ROWS_B, 256, 0, stream>>>(x, emb, ahp, e2g, hist, out0, out1, out2);
    entropy_kernel<<<1, NCODE, 0, stream>>>(hist, oent);
}

// Round 8
// 100.187 us; speedup vs baseline: 1.4931x; 1.4931x over previous
//
#include <hip/hip_runtime.h>
#include <hip/hip_bf16.h>
#include <math.h>

#define NROWS 131072
#define NCODE 512
#define DIM 128
#define ROWS_B 128

typedef __attribute__((ext_vector_type(8))) short short8v;
typedef __attribute__((ext_vector_type(16))) float f32x16;

__device__ inline short f2bf(float v) {
    __hip_bfloat16 h = __float2bfloat16(v);
    return *reinterpret_cast<short*>(&h);
}

// ||e||^2 per code (fp32 exact)
__global__ void e2_kernel(const float* __restrict__ emb, float* __restrict__ e2) {
    int c = blockIdx.x * blockDim.x + threadIdx.x;
    if (c < NCODE) {
        const float* e = emb + (size_t)c * DIM;
        float s = 0.f;
        #pragma unroll
        for (int l = 0; l < DIM; ++l) s = fmaf(e[l], e[l], s);
        e2[c] = s;
    }
}

// Pack emb into MFMA A-fragment lane order (bf16):
//   ahp[((mt*8)+kk)*64 + lane] = bf16(emb[code = mt*32 + (lane&31)][kk*16 + (lane>>5)*8 .. +8])
// -> vq_main A-loads are fully coalesced (64 lanes x 16B contiguous).
__global__ __launch_bounds__(256) void prep_pack(const float* __restrict__ emb,
        short8v* __restrict__ ahp) {
    int gid = blockIdx.x * 256 + threadIdx.x;       // 32 blocks x 256 = 8192
    int lane = gid & 63, kk = (gid >> 6) & 7, c32 = gid >> 9;
    int code = c32 * 32 + (lane & 31);
    int d0 = kk * 16 + (lane >> 5) * 8;
    const float* src = emb + (size_t)code * DIM + d0;
    float4 v0 = *reinterpret_cast<const float4*>(src);
    float4 v1 = *reinterpret_cast<const float4*>(src + 4);
    float f[8] = {v0.x, v0.y, v0.z, v0.w, v1.x, v1.y, v1.z, v1.w};
    short8v h;
    #pragma unroll
    for (int j = 0; j < 8; ++j) h[j] = f2bf(f[j]);
    ahp[gid] = h;
}

// D[m=code][n=row]; code = CB + (r&3) + 8*(r>>2) + 4*g, row = NT*32 + (lane&31).
#define PROC(ACC, CB, NT)                                                  \
    _Pragma("unroll")                                                      \
    for (int r = 0; r < 16; ++r) {                                         \
        int code = (CB) + (r & 3) + 8 * (r >> 2) + 4 * g;                  \
        float sv = e2s[code] - 2.0f * (ACC)[r];                            \
        if (sv < m1_##NT) { m1_##NT = sv; i1_##NT = code; }                \
    }

#define XMERGE(NT) {                                                       \
    float pm1 = __shfl_xor(m1_##NT, 32);                                   \
    int   pi  = __shfl_xor(i1_##NT, 32);                                   \
    bool pb = (pm1 < m1_##NT) || (pm1 == m1_##NT && pi < i1_##NT);         \
    if (pb) { m1_##NT = pm1; i1_##NT = pi; }                               \
}

__global__ __launch_bounds__(256, 3) void vq_main(
        const float* __restrict__ x, const float* __restrict__ emb,
        const short8v* __restrict__ ahp, const float* __restrict__ e2g,
        unsigned int* __restrict__ hist,
        float* __restrict__ out0, float* __restrict__ out1, float* __restrict__ out2) {
    __shared__ short xs[ROWS_B][DIM];   // XOR-swizzled: short index d ^ ((row&15)<<3)
    __shared__ float e2s[NCODE];
    __shared__ float x2s[ROWS_B];
    __shared__ float wm1[4][ROWS_B];
    __shared__ int   wi1[4][ROWS_B];
    __shared__ int   s_idx[ROWS_B];
    __shared__ float s_fin[ROWS_B];

    const int tid = threadIdx.x;
    const long row0 = (long)blockIdx.x * ROWS_B;

    // ---- stage x -> bf16 in LDS (swizzled), coalesced float4 ----
    const float4* xg = reinterpret_cast<const float4*>(x + row0 * DIM);
    #pragma unroll
    for (int it = 0; it < 16; ++it) {
        int i = tid + it * 256;
        int r = i >> 5, d0 = (i & 31) * 4;
        float4 v = xg[i];
        short4 h;
        h.x = f2bf(v.x); h.y = f2bf(v.y); h.z = f2bf(v.z); h.w = f2bf(v.w);
        int dd = d0 ^ ((r & 15) << 3);
        *reinterpret_cast<short4*>(&xs[r][dd]) = h;
    }
    for (int i = tid; i < NCODE; i += 256) e2s[i] = e2g[i];
    // ---- x2 per row (fp32 exact; L1/L2-hot re-read): 2 threads per row ----
    {
        int r = tid >> 1, q = tid & 1;
        const float4* xr = reinterpret_cast<const float4*>(x + (row0 + r) * DIM + q * 64);
        float s = 0.f;
        #pragma unroll
        for (int jj = 0; jj < 16; ++jj) {
            float4 v = xr[jj];
            s = fmaf(v.x, v.x, s); s = fmaf(v.y, v.y, s);
            s = fmaf(v.z, v.z, s); s = fmaf(v.w, v.w, s);
        }
        s += __shfl_down(s, 1, 64);
        if (q == 0) x2s[r] = s;
    }
    __syncthreads();

    const int wv = tid >> 6, lane = tid & 63;
    const int l31 = lane & 31, g = lane >> 5;
    const int bsw = (l31 & 15) << 3;

    float m1_0 = 1e30f; int i1_0 = 0;
    float m1_1 = 1e30f; int i1_1 = 0;
    float m1_2 = 1e30f; int i1_2 = 0;
    float m1_3 = 1e30f; int i1_3 = 0;

    // ---- wave wv owns codes [wv*128, wv*128+128): 4 M-tiles x all 128 rows ----
    // per kk-step: 1 coalesced A-load feeds 4 MFMAs (B from LDS, cheap).
    // unroll 2 (NOT full): full unroll hoists 8 kk-steps' loads -> spills (round 7).
    #pragma unroll 1
    for (int cc = 0; cc < 4; ++cc) {
        const int mt = wv * 4 + cc;
        f32x16 a0 = {}, a1 = {}, a2 = {}, a3 = {};

        #pragma unroll 2
        for (int kk = 0; kk < 8; ++kk) {
            short8v ah = ahp[(mt * 8 + kk) * 64 + lane];

            const int dd = (kk * 16 + g * 8) ^ bsw;
            short8v bh0 = *reinterpret_cast<const short8v*>(&xs[l31][dd]);
            short8v bh1 = *reinterpret_cast<const short8v*>(&xs[32 + l31][dd]);
            short8v bh2 = *reinterpret_cast<const short8v*>(&xs[64 + l31][dd]);
            short8v bh3 = *reinterpret_cast<const short8v*>(&xs[96 + l31][dd]);

            a0 = __builtin_amdgcn_mfma_f32_32x32x16_bf16(ah, bh0, a0, 0, 0, 0);
            a1 = __builtin_amdgcn_mfma_f32_32x32x16_bf16(ah, bh1, a1, 0, 0, 0);
            a2 = __builtin_amdgcn_mfma_f32_32x32x16_bf16(ah, bh2, a2, 0, 0, 0);
            a3 = __builtin_amdgcn_mfma_f32_32x32x16_bf16(ah, bh3, a3, 0, 0, 0);
        }
        const int cb = mt * 32;
        PROC(a0, cb, 0)
        PROC(a1, cb, 1)
        PROC(a2, cb, 2)
        PROC(a3, cb, 3)
    }

    // merge complementary code-halves (lane r <-> r+32, same row)
    XMERGE(0)
    XMERGE(1)
    XMERGE(2)
    XMERGE(3)
    if (lane < 32) {
        wm1[wv][l31]      = m1_0; wi1[wv][l31]      = i1_0;
        wm1[wv][32 + l31] = m1_1; wi1[wv][32 + l31] = i1_1;
        wm1[wv][64 + l31] = m1_2; wi1[wv][64 + l31] = i1_2;
        wm1[wv][96 + l31] = m1_3; wi1[wv][96 + l31] = i1_3;
    }
    __syncthreads();

    // ---- cross-wave merge (4 code-groups) ----
    if (tid < ROWS_B) {
        float m1 = wm1[0][tid]; int i1 = wi1[0][tid];
        #pragma unroll
        for (int w = 1; w < 4; ++w) {
            float pm1 = wm1[w][tid]; int pi = wi1[w][tid];
            bool pb = (pm1 < m1) || (pm1 == m1 && pi < i1);
            if (pb) { m1 = pm1; i1 = pi; }
        }
        s_idx[tid] = i1; s_fin[tid] = m1;
    }
    __syncthreads();

    // ---- out0: gather selected codebook rows (exact fp32) ----
    float4* o0 = reinterpret_cast<float4*>(out0 + row0 * DIM);
    #pragma unroll
    for (int it = 0; it < 16; ++it) {
        int i = tid + it * 256;
        int r = i >> 5, j = i & 31;
        int code = s_idx[r];
        o0[i] = reinterpret_cast<const float4*>(emb + (size_t)code * DIM)[j];
    }
    // ---- out1/out2 + histogram ----
    if (tid < ROWS_B) {
        float o = x2s[tid] + s_fin[tid];   // ||x||^2 + (||e||^2 - 2 x.e); err ~1e-4 << 4.24
        out1[row0 + tid] = o;
        out2[row0 + tid] = o;
        atomicAdd(&hist[s_idx[tid]], 1u);
    }
}

__global__ void entropy_kernel(const unsigned int* __restrict__ hist, float* __restrict__ oent) {
    __shared__ float red[8];
    int tid = threadIdx.x;  // 512 threads
    float p = (float)hist[tid] * (1.0f / 131072.0f);
    float t = (p > 0.f) ? (-p * logf(p)) : 0.f;
    #pragma unroll
    for (int off = 32; off > 0; off >>= 1) t += __shfl_down(t, off);
    if ((tid & 63) == 0) red[tid >> 6] = t;
    __syncthreads();
    if (tid == 0) {
        float s = 0.f;
        #pragma unroll
        for (int i = 0; i < 8; ++i) s += red[i];
        *oent = s;
    }
}

extern "C" void kernel_launch(void* const* d_in, const int* in_sizes, int n_in,
                              void* d_out, int out_size, void* d_ws, size_t ws_size,
                              hipStream_t stream) {
    const float* x   = (const float*)d_in[0];
    const float* emb = (const float*)d_in[1];
    float* out  = (float*)d_out;
    float* out0 = out;
    float* out1 = out0 + (size_t)NROWS * DIM;
    float* out2 = out1 + NROWS;
    float* oent = out2 + NROWS;

    unsigned int* hist = (unsigned int*)d_ws;
    float* e2g = (float*)((char*)d_ws + 4096);
    short8v* ahp = (short8v*)((char*)d_ws + 8192);

    hipMemsetAsync(d_ws, 0, 4096, stream);   // zero histogram (ws is poisoned, not re-zeroed)
    e2_kernel<<<2, 256, 0, stream>>>(emb, e2g);
    prep_pack<<<32, 256, 0, stream>>>(emb, ahp);
    vq_main<<<NROWS / ROWS_B, 256, 0, stream>>>(x, emb, ahp, e2g, hist, out0, out1, out2);
    entropy_kernel<<<1, NCODE, 0, stream>>>(hist, oent);
}

// Round 9
// 70.486 us; speedup vs baseline: 2.1223x; 1.4214x over previous
//
#include <hip/hip_runtime.h>
#include <hip/hip_bf16.h>
#include <math.h>

#define NROWS 131072
#define NCODE 512
#define DIM 128

typedef __attribute__((ext_vector_type(8))) short short8v;
typedef __attribute__((ext_vector_type(16))) float f32x16;

__device__ inline short f2bf(float v) {
    __hip_bfloat16 h = __float2bfloat16(v);
    return *reinterpret_cast<short*>(&h);
}

// ||e||^2 per code, written in D-fragment order:
//   e2p[mt*32 + g*16 + r] = e2[mt*32 + (r&3) + 8*(r>>2) + 4*g]
// so vq_argmin reads 4 uniform float4s per M-tile.
__global__ void e2p_kernel(const float* __restrict__ emb, float* __restrict__ e2p) {
    int code = blockIdx.x * blockDim.x + threadIdx.x;
    if (code < NCODE) {
        const float4* e = reinterpret_cast<const float4*>(emb + (size_t)code * DIM);
        float s = 0.f;
        #pragma unroll
        for (int j = 0; j < 32; ++j) {
            float4 v = e[j];
            s = fmaf(v.x, v.x, s); s = fmaf(v.y, v.y, s);
            s = fmaf(v.z, v.z, s); s = fmaf(v.w, v.w, s);
        }
        int mt = code >> 5, c5 = code & 31;
        int g = (c5 >> 2) & 1;
        int r = (c5 & 3) | ((c5 >> 3) << 2);
        e2p[mt * 32 + g * 16 + r] = s;
    }
}

// Pack emb into MFMA A-fragment lane order (bf16):
//   ahp[(mt*8+kk)*64 + lane] = bf16(emb[code = mt*32 + (lane&31)][kk*16 + (lane>>5)*8 .. +8])
__global__ __launch_bounds__(256) void prep_pack(const float* __restrict__ emb,
        short8v* __restrict__ ahp) {
    int gid = blockIdx.x * 256 + threadIdx.x;       // 32 blocks x 256 = 8192
    int lane = gid & 63, kk = (gid >> 6) & 7, c32 = gid >> 9;
    int code = c32 * 32 + (lane & 31);
    int d0 = kk * 16 + (lane >> 5) * 8;
    const float* src = emb + (size_t)code * DIM + d0;
    float4 v0 = *reinterpret_cast<const float4*>(src);
    float4 v1 = *reinterpret_cast<const float4*>(src + 4);
    float f[8] = {v0.x, v0.y, v0.z, v0.w, v1.x, v1.y, v1.z, v1.w};
    short8v h;
    #pragma unroll
    for (int j = 0; j < 8; ++j) h[j] = f2bf(f[j]);
    ahp[gid] = h;
}

// Wave-autonomous argmin: each wave owns 32 rows (B-frags in registers),
// streams all 512 codes' A-frags from L2. No LDS, no barriers.
__global__ __launch_bounds__(256, 4) void vq_argmin(
        const float* __restrict__ x, const short8v* __restrict__ ahp,
        const float* __restrict__ e2p, int* __restrict__ idxg,
        float* __restrict__ out1, float* __restrict__ out2) {
    const int tid = threadIdx.x;
    const int lane = tid & 63, l31 = lane & 31, g = lane >> 5;
    const int wid = blockIdx.x * 4 + (tid >> 6);
    const long rowbase = (long)wid * 32;

    // ---- load this lane's row half into B-fragments (fp32 -> bf16), fuse x2 ----
    short8v bh0, bh1, bh2, bh3, bh4, bh5, bh6, bh7;
    float xsq = 0.f;
    {
        const float* xrow = x + (rowbase + l31) * DIM + g * 8;
        #define LOADB(KK, BH) {                                            \
            float4 v0 = *reinterpret_cast<const float4*>(xrow + KK * 16);  \
            float4 v1 = *reinterpret_cast<const float4*>(xrow + KK * 16 + 4); \
            xsq = fmaf(v0.x, v0.x, xsq); xsq = fmaf(v0.y, v0.y, xsq);      \
            xsq = fmaf(v0.z, v0.z, xsq); xsq = fmaf(v0.w, v0.w, xsq);      \
            xsq = fmaf(v1.x, v1.x, xsq); xsq = fmaf(v1.y, v1.y, xsq);      \
            xsq = fmaf(v1.z, v1.z, xsq); xsq = fmaf(v1.w, v1.w, xsq);      \
            BH[0] = f2bf(v0.x); BH[1] = f2bf(v0.y);                        \
            BH[2] = f2bf(v0.z); BH[3] = f2bf(v0.w);                        \
            BH[4] = f2bf(v1.x); BH[5] = f2bf(v1.y);                        \
            BH[6] = f2bf(v1.z); BH[7] = f2bf(v1.w); }
        LOADB(0, bh0) LOADB(1, bh1) LOADB(2, bh2) LOADB(3, bh3)
        LOADB(4, bh4) LOADB(5, bh5) LOADB(6, bh6) LOADB(7, bh7)
        #undef LOADB
        xsq += __shfl_xor(xsq, 32);   // complementary k-chunks -> full ||x_row||^2
    }

    float m1 = 1e30f;
    int i1 = 0;

    // ---- stream 16 M-tiles x 8 k-steps of codes; 1 acc tile live ----
    #pragma unroll 1
    for (int mt = 0; mt < 16; ++mt) {
        const short8v* ap = ahp + mt * 512 + lane;
        f32x16 acc = {};
        acc = __builtin_amdgcn_mfma_f32_32x32x16_bf16(ap[0 * 64], bh0, acc, 0, 0, 0);
        acc = __builtin_amdgcn_mfma_f32_32x32x16_bf16(ap[1 * 64], bh1, acc, 0, 0, 0);
        acc = __builtin_amdgcn_mfma_f32_32x32x16_bf16(ap[2 * 64], bh2, acc, 0, 0, 0);
        acc = __builtin_amdgcn_mfma_f32_32x32x16_bf16(ap[3 * 64], bh3, acc, 0, 0, 0);
        acc = __builtin_amdgcn_mfma_f32_32x32x16_bf16(ap[4 * 64], bh4, acc, 0, 0, 0);
        acc = __builtin_amdgcn_mfma_f32_32x32x16_bf16(ap[5 * 64], bh5, acc, 0, 0, 0);
        acc = __builtin_amdgcn_mfma_f32_32x32x16_bf16(ap[6 * 64], bh6, acc, 0, 0, 0);
        acc = __builtin_amdgcn_mfma_f32_32x32x16_bf16(ap[7 * 64], bh7, acc, 0, 0, 0);

        const float4* ev = reinterpret_cast<const float4*>(e2p + mt * 32 + g * 16);
        float4 e0 = ev[0], e1 = ev[1], e2q = ev[2], e3 = ev[3];
        float earr[16] = {e0.x, e0.y, e0.z, e0.w, e1.x, e1.y, e1.z, e1.w,
                          e2q.x, e2q.y, e2q.z, e2q.w, e3.x, e3.y, e3.z, e3.w};
        const int base = mt * 32 + 4 * g;
        #pragma unroll
        for (int r = 0; r < 16; ++r) {
            float sv = earr[r] - 2.0f * acc[r];
            int code = base + (r & 3) + 8 * (r >> 2);
            if (sv < m1) { m1 = sv; i1 = code; }
        }
    }

    // merge the two g-halves (same row on lane and lane^32)
    {
        float pm = __shfl_xor(m1, 32);
        int   pi = __shfl_xor(i1, 32);
        if (pm < m1 || (pm == m1 && pi < i1)) { m1 = pm; i1 = pi; }
    }
    if (lane < 32) {
        long row = rowbase + l31;
        idxg[row] = i1;
        float o = xsq + m1;     // ||x||^2 + (||e||^2 - 2 x.e); err << 4.24 threshold
        out1[row] = o;
        out2[row] = o;
    }
}

// Pure streaming gather: out0[row] = emb[idx[row]] (exact fp32)
__global__ __launch_bounds__(256) void gather_kernel(const float* __restrict__ emb,
        const int* __restrict__ idxg, float* __restrict__ out0) {
    const float4* e4 = reinterpret_cast<const float4*>(emb);
    float4* o4 = reinterpret_cast<float4*>(out0);
    #pragma unroll
    for (int u = 0; u < 2; ++u) {
        int i = blockIdx.x * 512 + u * 256 + threadIdx.x;   // float4 index
        int row = i >> 5, j = i & 31;
        int c = idxg[row];
        o4[i] = e4[c * 32 + j];
    }
}

// Histogram (LDS) + entropy in one block; removes all global atomics.
__global__ __launch_bounds__(1024) void hist_entropy(const int* __restrict__ idxg,
        float* __restrict__ oent) {
    __shared__ int h[NCODE];
    __shared__ float red[16];
    int tid = threadIdx.x;
    if (tid < NCODE) h[tid] = 0;
    __syncthreads();
    const int4* i4 = reinterpret_cast<const int4*>(idxg);
    #pragma unroll
    for (int k = 0; k < 32; ++k) {
        int4 v = i4[tid + k * 1024];
        atomicAdd(&h[v.x], 1); atomicAdd(&h[v.y], 1);
        atomicAdd(&h[v.z], 1); atomicAdd(&h[v.w], 1);
    }
    __syncthreads();
    float t = 0.f;
    if (tid < NCODE) {
        float p = (float)h[tid] * (1.0f / 131072.0f);
        t = (p > 0.f) ? (-p * logf(p)) : 0.f;
    }
    #pragma unroll
    for (int off = 32; off > 0; off >>= 1) t += __shfl_down(t, off);
    if ((tid & 63) == 0) red[tid >> 6] = t;
    __syncthreads();
    if (tid == 0) {
        float s = 0.f;
        #pragma unroll
        for (int i = 0; i < 16; ++i) s += red[i];
        *oent = s;
    }
}

extern "C" void kernel_launch(void* const* d_in, const int* in_sizes, int n_in,
                              void* d_out, int out_size, void* d_ws, size_t ws_size,
                              hipStream_t stream) {
    const float* x   = (const float*)d_in[0];
    const float* emb = (const float*)d_in[1];
    float* out  = (float*)d_out;
    float* out0 = out;
    float* out1 = out0 + (size_t)NROWS * DIM;
    float* out2 = out1 + NROWS;
    float* oent = out2 + NROWS;

    float*   e2p = (float*)d_ws;                               // 2 KB
    short8v* ahp = (short8v*)((char*)d_ws + 4096);             // 128 KB
    int*     idxg = (int*)((char*)d_ws + 4096 + 131072);       // 512 KB

    e2p_kernel<<<2, 256, 0, stream>>>(emb, e2p);
    prep_pack<<<32, 256, 0, stream>>>(emb, ahp);
    vq_argmin<<<NROWS / 128, 256, 0, stream>>>(x, ahp, e2p, idxg, out1, out2);
    gather_kernel<<<NROWS * DIM / 4 / 512, 256, 0, stream>>>(emb, idxg, out0);
    hist_entropy<<<1, 1024, 0, stream>>>(idxg, oent);
}

// Round 10
// 65.678 us; speedup vs baseline: 2.2777x; 1.0732x over previous
//
#include <hip/hip_runtime.h>
#include <hip/hip_bf16.h>
#include <math.h>

#define NROWS 131072
#define NCODE 512
#define DIM 128

typedef __attribute__((ext_vector_type(8))) short short8v;
typedef __attribute__((ext_vector_type(16))) float f32x16;

__device__ inline short f2bf(float v) {
    __hip_bfloat16 h = __float2bfloat16(v);
    return *reinterpret_cast<short*>(&h);
}

// ||e||^2 per code, written in D-fragment order:
//   e2p[mt*32 + g*16 + r] = e2[mt*32 + (r&3) + 8*(r>>2) + 4*g]
__global__ void e2p_kernel(const float* __restrict__ emb, float* __restrict__ e2p) {
    int code = blockIdx.x * blockDim.x + threadIdx.x;
    if (code < NCODE) {
        const float4* e = reinterpret_cast<const float4*>(emb + (size_t)code * DIM);
        float s = 0.f;
        #pragma unroll
        for (int j = 0; j < 32; ++j) {
            float4 v = e[j];
            s = fmaf(v.x, v.x, s); s = fmaf(v.y, v.y, s);
            s = fmaf(v.z, v.z, s); s = fmaf(v.w, v.w, s);
        }
        int mt = code >> 5, c5 = code & 31;
        int g = (c5 >> 2) & 1;
        int r = (c5 & 3) | ((c5 >> 3) << 2);
        e2p[mt * 32 + g * 16 + r] = s;
    }
}

// Pack emb into MFMA A-fragment lane order (bf16):
//   ahp[(mt*8+kk)*64 + lane] = bf16(emb[code = mt*32 + (lane&31)][kk*16 + (lane>>5)*8 .. +8])
__global__ __launch_bounds__(256) void prep_pack(const float* __restrict__ emb,
        short8v* __restrict__ ahp) {
    int gid = blockIdx.x * 256 + threadIdx.x;       // 32 blocks x 256 = 8192
    int lane = gid & 63, kk = (gid >> 6) & 7, c32 = gid >> 9;
    int code = c32 * 32 + (lane & 31);
    int d0 = kk * 16 + (lane >> 5) * 8;
    const float* src = emb + (size_t)code * DIM + d0;
    float4 v0 = *reinterpret_cast<const float4*>(src);
    float4 v1 = *reinterpret_cast<const float4*>(src + 4);
    float f[8] = {v0.x, v0.y, v0.z, v0.w, v1.x, v1.y, v1.z, v1.w};
    short8v h;
    #pragma unroll
    for (int j = 0; j < 8; ++j) h[j] = f2bf(f[j]);
    ahp[gid] = h;
}

// Wave-autonomous argmin + fused gather: each wave owns 32 rows (B-frags in
// registers), streams all 512 codes' A-frags from L2, then writes out0 itself.
// No LDS, no barriers.
__global__ __launch_bounds__(256, 4) void vq_argmin(
        const float* __restrict__ x, const float* __restrict__ emb,
        const short8v* __restrict__ ahp, const float* __restrict__ e2p,
        int* __restrict__ idxg,
        float* __restrict__ out0, float* __restrict__ out1, float* __restrict__ out2) {
    const int tid = threadIdx.x;
    const int lane = tid & 63, l31 = lane & 31, g = lane >> 5;
    const int wid = blockIdx.x * 4 + (tid >> 6);
    const long rowbase = (long)wid * 32;

    // ---- load this lane's row half into B-fragments (fp32 -> bf16), fuse x2 ----
    short8v bh0, bh1, bh2, bh3, bh4, bh5, bh6, bh7;
    float xsq = 0.f;
    {
        const float* xrow = x + (rowbase + l31) * DIM + g * 8;
        #define LOADB(KK, BH) {                                            \
            float4 v0 = *reinterpret_cast<const float4*>(xrow + KK * 16);  \
            float4 v1 = *reinterpret_cast<const float4*>(xrow + KK * 16 + 4); \
            xsq = fmaf(v0.x, v0.x, xsq); xsq = fmaf(v0.y, v0.y, xsq);      \
            xsq = fmaf(v0.z, v0.z, xsq); xsq = fmaf(v0.w, v0.w, xsq);      \
            xsq = fmaf(v1.x, v1.x, xsq); xsq = fmaf(v1.y, v1.y, xsq);      \
            xsq = fmaf(v1.z, v1.z, xsq); xsq = fmaf(v1.w, v1.w, xsq);      \
            BH[0] = f2bf(v0.x); BH[1] = f2bf(v0.y);                        \
            BH[2] = f2bf(v0.z); BH[3] = f2bf(v0.w);                        \
            BH[4] = f2bf(v1.x); BH[5] = f2bf(v1.y);                        \
            BH[6] = f2bf(v1.z); BH[7] = f2bf(v1.w); }
        LOADB(0, bh0) LOADB(1, bh1) LOADB(2, bh2) LOADB(3, bh3)
        LOADB(4, bh4) LOADB(5, bh5) LOADB(6, bh6) LOADB(7, bh7)
        #undef LOADB
        xsq += __shfl_xor(xsq, 32);   // complementary k-chunks -> full ||x_row||^2
    }

    float m1 = 1e30f;
    int i1 = 0;

    // ---- stream 16 M-tiles x 8 k-steps; unroll 2 -> two independent acc
    // chains, 16 A-loads in flight (VGPR ~115 < 128 cap; full unroll spills) ----
    #pragma unroll 2
    for (int mt = 0; mt < 16; ++mt) {
        const short8v* ap = ahp + mt * 512 + lane;
        f32x16 acc = {};
        acc = __builtin_amdgcn_mfma_f32_32x32x16_bf16(ap[0 * 64], bh0, acc, 0, 0, 0);
        acc = __builtin_amdgcn_mfma_f32_32x32x16_bf16(ap[1 * 64], bh1, acc, 0, 0, 0);
        acc = __builtin_amdgcn_mfma_f32_32x32x16_bf16(ap[2 * 64], bh2, acc, 0, 0, 0);
        acc = __builtin_amdgcn_mfma_f32_32x32x16_bf16(ap[3 * 64], bh3, acc, 0, 0, 0);
        acc = __builtin_amdgcn_mfma_f32_32x32x16_bf16(ap[4 * 64], bh4, acc, 0, 0, 0);
        acc = __builtin_amdgcn_mfma_f32_32x32x16_bf16(ap[5 * 64], bh5, acc, 0, 0, 0);
        acc = __builtin_amdgcn_mfma_f32_32x32x16_bf16(ap[6 * 64], bh6, acc, 0, 0, 0);
        acc = __builtin_amdgcn_mfma_f32_32x32x16_bf16(ap[7 * 64], bh7, acc, 0, 0, 0);

        const float4* ev = reinterpret_cast<const float4*>(e2p + mt * 32 + g * 16);
        float4 e0 = ev[0], e1 = ev[1], e2q = ev[2], e3 = ev[3];
        float earr[16] = {e0.x, e0.y, e0.z, e0.w, e1.x, e1.y, e1.z, e1.w,
                          e2q.x, e2q.y, e2q.z, e2q.w, e3.x, e3.y, e3.z, e3.w};
        const int base = mt * 32 + 4 * g;
        #pragma unroll
        for (int r = 0; r < 16; ++r) {
            float sv = earr[r] - 2.0f * acc[r];
            int code = base + (r & 3) + 8 * (r >> 2);
            if (sv < m1) { m1 = sv; i1 = code; }
        }
    }

    // merge the two g-halves (same row on lane and lane^32)
    {
        float pm = __shfl_xor(m1, 32);
        int   pi = __shfl_xor(i1, 32);
        if (pm < m1 || (pm == m1 && pi < i1)) { m1 = pm; i1 = pi; }
    }
    if (lane < 32) {
        long row = rowbase + l31;
        idxg[row] = i1;
        float o = xsq + m1;     // ||x||^2 + (||e||^2 - 2 x.e); err << 4.24 threshold
        out1[row] = o;
        out2[row] = o;
    }

    // ---- fused gather: out0[row] = emb[idx[row]], 2 rows/iter (half-wave each).
    // emb is L2-hot (256 KB); writes 512 B coalesced per half-wave. ----
    {
        const float4* e4 = reinterpret_cast<const float4*>(emb);
        float4* o4 = reinterpret_cast<float4*>(out0) + rowbase * 32;
        #pragma unroll 4
        for (int rr = 0; rr < 32; rr += 2) {
            int c0 = __shfl(i1, rr);
            int c1 = __shfl(i1, rr + 1);
            int c = g ? c1 : c0;
            int r = rr + g;
            o4[r * 32 + l31] = e4[c * 32 + l31];
        }
    }
}

// Histogram (LDS) + entropy in one block.
__global__ __launch_bounds__(1024) void hist_entropy(const int* __restrict__ idxg,
        float* __restrict__ oent) {
    __shared__ int h[NCODE];
    __shared__ float red[16];
    int tid = threadIdx.x;
    if (tid < NCODE) h[tid] = 0;
    __syncthreads();
    const int4* i4 = reinterpret_cast<const int4*>(idxg);
    #pragma unroll
    for (int k = 0; k < 32; ++k) {
        int4 v = i4[tid + k * 1024];
        atomicAdd(&h[v.x], 1); atomicAdd(&h[v.y], 1);
        atomicAdd(&h[v.z], 1); atomicAdd(&h[v.w], 1);
    }
    __syncthreads();
    float t = 0.f;
    if (tid < NCODE) {
        float p = (float)h[tid] * (1.0f / 131072.0f);
        t = (p > 0.f) ? (-p * logf(p)) : 0.f;
    }
    #pragma unroll
    for (int off = 32; off > 0; off >>= 1) t += __shfl_down(t, off);
    if ((tid & 63) == 0) red[tid >> 6] = t;
    __syncthreads();
    if (tid == 0) {
        float s = 0.f;
        #pragma unroll
        for (int i = 0; i < 16; ++i) s += red[i];
        *oent = s;
    }
}

extern "C" void kernel_launch(void* const* d_in, const int* in_sizes, int n_in,
                              void* d_out, int out_size, void* d_ws, size_t ws_size,
                              hipStream_t stream) {
    const float* x   = (const float*)d_in[0];
    const float* emb = (const float*)d_in[1];
    float* out  = (float*)d_out;
    float* out0 = out;
    float* out1 = out0 + (size_t)NROWS * DIM;
    float* out2 = out1 + NROWS;
    float* oent = out2 + NROWS;

    float*   e2p = (float*)d_ws;                               // 2 KB
    short8v* ahp = (short8v*)((char*)d_ws + 4096);             // 128 KB
    int*     idxg = (int*)((char*)d_ws + 4096 + 131072);       // 512 KB

    e2p_kernel<<<2, 256, 0, stream>>>(emb, e2p);
    prep_pack<<<32, 256, 0, stream>>>(emb, ahp);
    vq_argmin<<<NROWS / 128, 256, 0, stream>>>(x, emb, ahp, e2p, idxg, out0, out1, out2);
    hist_entropy<<<1, 1024, 0, stream>>>(idxg, oent);
}